// Round 6
// baseline (1009.353 us; speedup 1.0000x reference)
//
#include <hip/hip_runtime.h>
#include <math.h>

#define CUTOFF_INV 0.2f
#define EPB_SHIFT 11
#define EPB 2048
#define NBIN_MAX 512
#define FLUSH 8

typedef unsigned int uint;

__device__ __forceinline__ float fcut(float r) {
    // 1 - 6p^5 + 15p^4 - 10p^3, p = r/cutoff
    float p = r * CUTOFF_INV;
    float p2 = p * p;
    float p3 = p2 * p;
    return 1.0f + p3 * (-10.0f + p * (15.0f - 6.0f * p));
}

// spherical-plus-norm legendre factors: s_l = sqrt((2l+1)/pi) * P_l(ca)
__device__ __forceinline__ void legendre_s(float ca, float& s0, float& s1, float& s2) {
    s0 = 0.5641895835477563f;
    s1 = 0.9772050238058398f * ca;
    s2 = 1.2615662610100802f * (1.5f * ca * ca - 0.5f);
}

// ---------------- Stage 1: node gate = sigmoid(nf @ W1 + b1) -> [N,9] ----------------
__global__ void node_gate_kernel(const float* __restrict__ nf,
                                 const float* __restrict__ W1,
                                 const float* __restrict__ b1,
                                 float* __restrict__ gate, int N) {
    __shared__ float sW[64 * 9];
    __shared__ float sb[9];
    for (int i = threadIdx.x; i < 576; i += blockDim.x) sW[i] = W1[i];
    if (threadIdx.x < 9) sb[threadIdx.x] = b1[threadIdx.x];
    __syncthreads();
    int t = blockIdx.x * blockDim.x + threadIdx.x;
    if (t >= N) return;
    float acc[9];
#pragma unroll
    for (int d = 0; d < 9; ++d) acc[d] = sb[d];
    const float* row = nf + (size_t)t * 64;
#pragma unroll
    for (int f = 0; f < 64; ++f) {
        float x = row[f];
#pragma unroll
        for (int d = 0; d < 9; ++d) acc[d] += x * sW[f * 9 + d];
    }
#pragma unroll
    for (int d = 0; d < 9; ++d)
        gate[(size_t)t * 9 + d] = 1.0f / (1.0f + __expf(-acc[d]));
}

// ---------------- Stage 2a: per-edge radial table, 16-float (64B) aligned rows ----------------
// A[e][l*3+n] = j_l(z_{l,n} rik/c) * fc(rik) * gate[nk][l,n]; cols 9..15 zero.
__global__ void edge_A16_kernel(const float* __restrict__ dist,
                                const int* __restrict__ eidx,   // [2,E]
                                const float* __restrict__ gate, // [N,9]
                                float* __restrict__ A,          // [E,16]
                                int E) {
    int e = blockIdx.x * blockDim.x + threadIdx.x;
    if (e >= E) return;
    float rik = dist[e];
    float fcik = fcut(rik);
    int nk = eidx[E + e];
    const float* g = gate + (size_t)nk * 9;
    float rr = rik * CUTOFF_INV;
    float v[9];

    {   // l = 0: j0 = sin(x)/x
        const float Z0[3] = {3.14159265358979324f, 6.28318530717958648f, 9.42477796076937972f};
#pragma unroll
        for (int n = 0; n < 3; ++n) {
            float x = Z0[n] * rr;
            v[n] = (__sinf(x) / x) * fcik * g[n];
        }
    }
    {   // l = 1: j1 = (sin/x - cos)/x
        const float Z1[3] = {4.49340945790806150f, 7.72525183693865170f, 10.9041216594298970f};
#pragma unroll
        for (int n = 0; n < 3; ++n) {
            float x = Z1[n] * rr;
            float s, c;
            __sincosf(x, &s, &c);
            float invx = 1.0f / x;
            v[3 + n] = ((s * invx - c) * invx) * fcik * g[3 + n];
        }
    }
    {   // l = 2: j2 = 3/x*j1 - j0
        const float Z2[3] = {5.76345919689554900f, 9.09501133047736000f, 12.3229409705673230f};
#pragma unroll
        for (int n = 0; n < 3; ++n) {
            float x = Z2[n] * rr;
            float s, c;
            __sincosf(x, &s, &c);
            float invx = 1.0f / x;
            float sx = s * invx;
            float j1 = (sx - c) * invx;
            v[6 + n] = (3.0f * invx * j1 - sx) * fcik * g[6 + n];
        }
    }
    float4* out = (float4*)(A + ((size_t)e << 4));
    out[0] = make_float4(v[0], v[1], v[2], v[3]);
    out[1] = make_float4(v[4], v[5], v[6], v[7]);
    out[2] = make_float4(v[8], 0.0f, 0.0f, 0.0f);
    out[3] = make_float4(0.0f, 0.0f, 0.0f, 0.0f);
}

// overflow fallback: accumulate one record straight into global mid
__device__ __forceinline__ void spill_rec(uint2 rec, int bin,
                                          const float* __restrict__ A,
                                          float* __restrict__ mid) {
    float ca = __uint_as_float(rec.x);
    uint ik  = rec.y & 0xFFFFFu;
    uint ijl = rec.y >> 20;
    float s0, s1, s2;
    legendre_s(ca, s0, s1, s2);
    const float* a = A + ((size_t)ik << 4);
    float* dst = mid + ((size_t)bin * EPB + ijl) * 9;
    atomicAdd(dst + 0, a[0] * s0);
    atomicAdd(dst + 1, a[1] * s0);
    atomicAdd(dst + 2, a[2] * s0);
    atomicAdd(dst + 3, a[3] * s1);
    atomicAdd(dst + 4, a[4] * s1);
    atomicAdd(dst + 5, a[5] * s1);
    atomicAdd(dst + 6, a[6] * s2);
    atomicAdd(dst + 7, a[7] * s2);
    atomicAdd(dst + 8, a[8] * s2);
}

// ---------------- Pass 1: LDS multi-split binning of triplet records ----------------
// record = {f32 ca, (ij_local:12 | ik:20)}. LDS-staged per bin; flush 8 records
// (64B full line) with ONE global atomic. FLUSH=8 -> 34KB LDS -> 4 blocks/CU.
__global__ void __launch_bounds__(256) p1_bin_kernel(const float* __restrict__ ang,
                                                     const int* __restrict__ tidx, // [2,T]
                                                     uint* __restrict__ gcur,      // [NBIN]
                                                     uint2* __restrict__ binbuf,   // [NBIN*BCAP]
                                                     const float* __restrict__ A,
                                                     float* __restrict__ mid,
                                                     int T, int NBIN, int BCAP) {
    __shared__ uint bcnt[NBIN_MAX];
    __shared__ __align__(16) uint2 rbuf[NBIN_MAX * FLUSH];
    __shared__ int s_more;

    for (int i = threadIdx.x; i < NBIN; i += blockDim.x) bcnt[i] = 0;

    int chunk = (T + gridDim.x - 1) / gridDim.x;
    int t = blockIdx.x * chunk + threadIdx.x;
    int tend = min(T, blockIdx.x * chunk + chunk);

    bool have = false;
    uint2 rec;
    int bin = 0;
    __syncthreads();

    for (;;) {
        if (!have && t < tend) {
            int ij = tidx[t];
            int ik = tidx[T + t];
            float ca = ang[t];
            rec.x = __float_as_uint(ca);
            rec.y = ((uint)(ij & (EPB - 1)) << 20) | (uint)ik;
            bin = ij >> EPB_SHIFT;
            t += blockDim.x;
            have = true;
        }
        if (have) {
            uint pos = atomicAdd(&bcnt[bin], 1u);
            if (pos < FLUSH) {
                rbuf[bin * FLUSH + pos] = rec;
                have = false;
            } else {
                atomicSub(&bcnt[bin], 1u);   // full: retry next round after flush
            }
        }
        if (threadIdx.x == 0) s_more = 0;
        __syncthreads();
        if (have || t < tend) s_more = 1;    // benign race
        __syncthreads();                     // rbuf writes visible; s_more settled
        // flush full bins: one atomic + one 64B aligned full-line copy
        for (int b = threadIdx.x; b < NBIN; b += blockDim.x) {
            if (bcnt[b] == FLUSH) {
                uint base = atomicAdd(&gcur[b], (uint)FLUSH);
                if (base + FLUSH <= (uint)BCAP) {
                    const uint4* src = (const uint4*)&rbuf[b * FLUSH];
                    uint4* dst = (uint4*)(binbuf + (size_t)b * BCAP + base);
#pragma unroll
                    for (int q = 0; q < FLUSH / 2; ++q) dst[q] = src[q];
                } else {
#pragma unroll
                    for (int q = 0; q < FLUSH; ++q) spill_rec(rbuf[b * FLUSH + q], b, A, mid);
                }
                bcnt[b] = 0;
            }
        }
        __syncthreads();                     // protect rbuf reuse next round
        if (!s_more) break;
    }
    // drain partial bins
    for (int b = threadIdx.x; b < NBIN; b += blockDim.x) {
        uint c = bcnt[b];
        if (c > 0) {
            uint base = atomicAdd(&gcur[b], c);
            if (base + c <= (uint)BCAP) {
                for (uint q = 0; q < c; ++q)
                    binbuf[(size_t)b * BCAP + base + q] = rbuf[b * FLUSH + q];
            } else {
                for (uint q = 0; q < c; ++q) spill_rec(rbuf[b * FLUSH + q], b, A, mid);
            }
        }
    }
}

// ---------------- Pass 2 (fused): per-bin accumulate in LDS, then GatedMLP epilogue ----------------
// Gather phase: A[ik] gathers + LDS atomics (MSHR-bound, ~396us floor).
// Epilogue: wave-per-edge GatedMLP over the bin's 2048 contiguous edges; weights
// loaded once per block. Replaces the separate edge_kernel (250K block launches)
// and kills mid's 36MB write + 36MB re-read.
__global__ void __launch_bounds__(1024) p2_fused_kernel(const float* __restrict__ dist,
                                                        const float* __restrict__ A,     // [E,16]
                                                        const uint* __restrict__ gcur,   // [NBIN]
                                                        const uint2* __restrict__ binbuf,
                                                        const float* __restrict__ mid,   // [E,9] spill acc
                                                        const float* __restrict__ attr,
                                                        const float* __restrict__ Wm,
                                                        const float* __restrict__ bm,
                                                        const float* __restrict__ Wg,
                                                        const float* __restrict__ bg,
                                                        float* __restrict__ out,
                                                        int E, int BCAP) {
    __shared__ float lmid[EPB * 9];   // 72 KB
    __shared__ float sWm[576], sWg[576], sbm[64], sbg[64];
    for (int i = threadIdx.x; i < 576; i += blockDim.x) {
        sWm[i] = Wm[i];
        sWg[i] = Wg[i];
    }
    if (threadIdx.x < 64) {
        sbm[threadIdx.x] = bm[threadIdx.x];
        sbg[threadIdx.x] = bg[threadIdx.x];
    }
    int b = blockIdx.x;
    int ebase = b << EPB_SHIFT;
    int ecnt = min(EPB, E - ebase);
    for (int i = threadIdx.x; i < EPB * 9; i += blockDim.x) lmid[i] = 0.0f;
    __syncthreads();

    uint n = gcur[b];
    if (n > (uint)BCAP) n = (uint)BCAP;
    const uint2* rb = binbuf + (size_t)b * BCAP;
    uint bd = blockDim.x;
    uint i = threadIdx.x;

    for (; i + 3 * bd < n; i += 4 * bd) {
        uint2 r0 = rb[i];
        uint2 r1 = rb[i + bd];
        uint2 r2 = rb[i + 2 * bd];
        uint2 r3 = rb[i + 3 * bd];
        const float4* A0 = (const float4*)(A + ((size_t)(r0.y & 0xFFFFFu) << 4));
        const float4* A1 = (const float4*)(A + ((size_t)(r1.y & 0xFFFFFu) << 4));
        const float4* A2 = (const float4*)(A + ((size_t)(r2.y & 0xFFFFFu) << 4));
        const float4* A3 = (const float4*)(A + ((size_t)(r3.y & 0xFFFFFu) << 4));
        float4 a00 = A0[0], a01 = A0[1]; float a08 = *((const float*)(A0 + 2));
        float4 a10 = A1[0], a11 = A1[1]; float a18 = *((const float*)(A1 + 2));
        float4 a20 = A2[0], a21 = A2[1]; float a28 = *((const float*)(A2 + 2));
        float4 a30 = A3[0], a31 = A3[1]; float a38 = *((const float*)(A3 + 2));

#define ACC_ONE(rr, q0, q1, q8)                                       \
        {                                                             \
            float ca = __uint_as_float(rr.x);                         \
            uint ijl = rr.y >> 20;                                    \
            float s0, s1, s2;                                         \
            legendre_s(ca, s0, s1, s2);                               \
            float* d = &lmid[ijl * 9];                                \
            atomicAdd(d + 0, q0.x * s0);                              \
            atomicAdd(d + 1, q0.y * s0);                              \
            atomicAdd(d + 2, q0.z * s0);                              \
            atomicAdd(d + 3, q0.w * s1);                              \
            atomicAdd(d + 4, q1.x * s1);                              \
            atomicAdd(d + 5, q1.y * s1);                              \
            atomicAdd(d + 6, q1.z * s2);                              \
            atomicAdd(d + 7, q1.w * s2);                              \
            atomicAdd(d + 8, q8 * s2);                                \
        }

        ACC_ONE(r0, a00, a01, a08)
        ACC_ONE(r1, a10, a11, a18)
        ACC_ONE(r2, a20, a21, a28)
        ACC_ONE(r3, a30, a31, a38)
    }
    for (; i < n; i += bd) {
        uint2 rr = rb[i];
        const float4* Ar = (const float4*)(A + ((size_t)(rr.y & 0xFFFFFu) << 4));
        float4 q0 = Ar[0], q1 = Ar[1];
        float q8 = *((const float*)(Ar + 2));
        ACC_ONE(rr, q0, q1, q8)
    }
#undef ACC_ONE

    __syncthreads();
    // GatedMLP epilogue: wave per edge, lane = feature. attr/out coalesced.
    int wid  = threadIdx.x >> 6;
    int lane = threadIdx.x & 63;
    int nw   = blockDim.x >> 6;
    for (int el = wid; el < ecnt; el += nw) {
        int e = ebase + el;
        float fc = fcut(dist[e]);   // fc(rij) factored out of the triplet sum
        const float* ls = &lmid[el * 9];
        const float* mg = mid + (size_t)e * 9;   // spill contribution (usually 0)
        float am = sbm[lane], ag = sbg[lane];
#pragma unroll
        for (int d = 0; d < 9; ++d) {
            float ud = fc * (ls[d] + mg[d]);
            am += ud * sWm[d * 64 + lane];
            ag += ud * sWg[d * 64 + lane];
        }
        float h  = am / (1.0f + __expf(-am));   // silu
        float gt = 1.0f / (1.0f + __expf(-ag)); // sigmoid
        size_t off = (size_t)e * 64 + lane;
        out[off] = attr[off] + h * gt;
    }
}

// ---------------- Legacy fallback triplet kernel (round-1 path) ----------------
__global__ void triplet_kernel(const float* __restrict__ dist,
                               const float* __restrict__ ang,
                               const int* __restrict__ tidx,
                               const int* __restrict__ eidx,
                               const float* __restrict__ gate,
                               float* __restrict__ mid,
                               int T, int E) {
    int t = blockIdx.x * blockDim.x + threadIdx.x;
    if (t >= T) return;
    int ij = tidx[t];
    int ik = tidx[T + t];
    float ca  = ang[t];
    float rij = dist[ij];
    float rik = dist[ik];
    float fc = fcut(rij) * fcut(rik);
    float s0, s1, s2;
    legendre_s(ca, s0, s1, s2);
    s0 *= fc; s1 *= fc; s2 *= fc;
    int nk = eidx[E + ik];
    const float* g = gate + (size_t)nk * 9;
    float rr = rik * CUTOFF_INV;
    float v[9];
    {
        const float Z0[3] = {3.14159265358979324f, 6.28318530717958648f, 9.42477796076937972f};
#pragma unroll
        for (int n = 0; n < 3; ++n) {
            float x = Z0[n] * rr;
            v[n] = (__sinf(x) / x) * s0 * g[n];
        }
    }
    {
        const float Z1[3] = {4.49340945790806150f, 7.72525183693865170f, 10.9041216594298970f};
#pragma unroll
        for (int n = 0; n < 3; ++n) {
            float x = Z1[n] * rr;
            float s, c;
            __sincosf(x, &s, &c);
            float invx = 1.0f / x;
            v[3 + n] = ((s * invx - c) * invx) * s1 * g[3 + n];
        }
    }
    {
        const float Z2[3] = {5.76345919689554900f, 9.09501133047736000f, 12.3229409705673230f};
#pragma unroll
        for (int n = 0; n < 3; ++n) {
            float x = Z2[n] * rr;
            float s, c;
            __sincosf(x, &s, &c);
            float invx = 1.0f / x;
            float sx = s * invx;
            float j1 = (sx - c) * invx;
            v[6 + n] = (3.0f * invx * j1 - sx) * s2 * g[6 + n];
        }
    }
    float* dst = mid + (size_t)ij * 9;
#pragma unroll
    for (int d = 0; d < 9; ++d) atomicAdd(dst + d, v[d]);
}

// ---------------- Legacy Stage 3 (fallback path only) ----------------
__global__ void edge_kernel(const float* __restrict__ mid,
                            const float* __restrict__ attr,
                            const float* __restrict__ Wm, const float* __restrict__ bm,
                            const float* __restrict__ Wg, const float* __restrict__ bg,
                            float* __restrict__ out, int E) {
    __shared__ float sWm[9 * 64], sWg[9 * 64], sbm[64], sbg[64];
    for (int i = threadIdx.x; i < 576; i += blockDim.x) {
        sWm[i] = Wm[i];
        sWg[i] = Wg[i];
    }
    if (threadIdx.x < 64) {
        sbm[threadIdx.x] = bm[threadIdx.x];
        sbg[threadIdx.x] = bg[threadIdx.x];
    }
    __syncthreads();
    int wid  = threadIdx.x >> 6;
    int lane = threadIdx.x & 63;
    int e = blockIdx.x * (blockDim.x >> 6) + wid;
    if (e >= E) return;
    const float* u = mid + (size_t)e * 9;
    float am = sbm[lane], ag = sbg[lane];
#pragma unroll
    for (int d = 0; d < 9; ++d) {
        float ud = u[d];
        am += ud * sWm[d * 64 + lane];
        ag += ud * sWg[d * 64 + lane];
    }
    float h  = am / (1.0f + __expf(-am));
    float gt = 1.0f / (1.0f + __expf(-ag));
    size_t off = (size_t)e * 64 + lane;
    out[off] = attr[off] + h * gt;
}

extern "C" void kernel_launch(void* const* d_in, const int* in_sizes, int n_in,
                              void* d_out, int out_size, void* d_ws, size_t ws_size,
                              hipStream_t stream) {
    const float* dist = (const float*)d_in[0];
    const float* ang  = (const float*)d_in[1];
    const float* nf   = (const float*)d_in[2];
    const float* attr = (const float*)d_in[3];
    const float* W1   = (const float*)d_in[4];
    const float* b1   = (const float*)d_in[5];
    const float* Wm   = (const float*)d_in[6];
    const float* bm   = (const float*)d_in[7];
    const float* Wg   = (const float*)d_in[8];
    const float* bg   = (const float*)d_in[9];
    const int* tidx   = (const int*)d_in[10];
    const int* eidx   = (const int*)d_in[11];

    int E = in_sizes[0];
    int T = in_sizes[1];
    int N = in_sizes[2] / 64;

    int NBIN = (E + EPB - 1) >> EPB_SHIFT;
    int mean = T / (NBIN > 0 ? NBIN : 1);
    int BCAP = ((mean + mean / 8 + 512) + 15) & ~15;   // ~20 sigma headroom, 16-aligned

    // ws layout (floats): gate[N*9 pad16] | A[E*16] | mid[E*9] | gcur[NBIN] | pad | binbuf[NBIN*BCAP*2]
    size_t f_gate = ((size_t)N * 9 + 15) & ~(size_t)15;
    size_t o_A    = f_gate;
    size_t o_mid  = o_A + (size_t)E * 16;
    size_t o_gcur = o_mid + (size_t)E * 9;
    size_t o_bb   = (o_gcur + (size_t)NBIN + 15) & ~(size_t)15;   // 64B-align binbuf
    size_t total  = o_bb + (size_t)NBIN * BCAP * 2;

    bool newpath = (E <= (1 << 20)) && (NBIN <= NBIN_MAX) && (ws_size >= total * 4);

    float* gate = (float*)d_ws;

    if (newpath) {
        float* A      = gate + o_A;
        float* mid    = gate + o_mid;
        uint*  gcur   = (uint*)(gate + o_gcur);
        uint2* binbuf = (uint2*)(gate + o_bb);

        hipMemsetAsync(gcur, 0, (size_t)NBIN * sizeof(uint), stream);
        hipMemsetAsync(mid, 0, (size_t)E * 9 * sizeof(float), stream);
        node_gate_kernel<<<(N + 255) / 256, 256, 0, stream>>>(nf, W1, b1, gate, N);
        edge_A16_kernel<<<(E + 255) / 256, 256, 0, stream>>>(dist, eidx, gate, A, E);
        p1_bin_kernel<<<1024, 256, 0, stream>>>(ang, tidx, gcur, binbuf, A, mid, T, NBIN, BCAP);
        p2_fused_kernel<<<NBIN, 1024, 0, stream>>>(dist, A, gcur, binbuf, mid,
                                                   attr, Wm, bm, Wg, bg,
                                                   (float*)d_out, E, BCAP);
    } else {
        // legacy path (round-1)
        float* mid = gate + f_gate;
        hipMemsetAsync(mid, 0, (size_t)E * 9 * sizeof(float), stream);
        node_gate_kernel<<<(N + 255) / 256, 256, 0, stream>>>(nf, W1, b1, gate, N);
        triplet_kernel<<<(T + 255) / 256, 256, 0, stream>>>(dist, ang, tidx, eidx, gate, mid, T, E);
        edge_kernel<<<(E + 3) / 4, 256, 0, stream>>>(mid, attr, Wm, bm, Wg, bg, (float*)d_out, E);
    }
}

// Round 7
// 634.043 us; speedup vs baseline: 1.5919x; 1.5919x over previous
//
#include <hip/hip_runtime.h>
#include <math.h>

#define CUTOFF_INV 0.2f
#define EPB_SHIFT 11
#define EPB 2048
#define NBIN_MAX 512
#define P1_CHUNK 4096
#define P1_THREADS 512
#define GC_STRIDE 16   // gcount padding: 64B per counter (avoid same-line atomic serialization)

typedef unsigned int uint;
typedef unsigned short ushort;

__device__ __forceinline__ float fcut(float r) {
    // 1 - 6p^5 + 15p^4 - 10p^3, p = r/cutoff
    float p = r * CUTOFF_INV;
    float p2 = p * p;
    float p3 = p2 * p;
    return 1.0f + p3 * (-10.0f + p * (15.0f - 6.0f * p));
}

// spherical-plus-norm legendre factors: s_l = sqrt((2l+1)/pi) * P_l(ca)
__device__ __forceinline__ void legendre_s(float ca, float& s0, float& s1, float& s2) {
    s0 = 0.5641895835477563f;
    s1 = 0.9772050238058398f * ca;
    s2 = 1.2615662610100802f * (1.5f * ca * ca - 0.5f);
}

// ---------------- Stage 1: node gate = sigmoid(nf @ W1 + b1) -> [N,9] ----------------
__global__ void node_gate_kernel(const float* __restrict__ nf,
                                 const float* __restrict__ W1,
                                 const float* __restrict__ b1,
                                 float* __restrict__ gate, int N) {
    __shared__ float sW[64 * 9];
    __shared__ float sb[9];
    for (int i = threadIdx.x; i < 576; i += blockDim.x) sW[i] = W1[i];
    if (threadIdx.x < 9) sb[threadIdx.x] = b1[threadIdx.x];
    __syncthreads();
    int t = blockIdx.x * blockDim.x + threadIdx.x;
    if (t >= N) return;
    float acc[9];
#pragma unroll
    for (int d = 0; d < 9; ++d) acc[d] = sb[d];
    const float* row = nf + (size_t)t * 64;
#pragma unroll
    for (int f = 0; f < 64; ++f) {
        float x = row[f];
#pragma unroll
        for (int d = 0; d < 9; ++d) acc[d] += x * sW[f * 9 + d];
    }
#pragma unroll
    for (int d = 0; d < 9; ++d)
        gate[(size_t)t * 9 + d] = 1.0f / (1.0f + __expf(-acc[d]));
}

// ---------------- Stage 2a: per-edge radial table, 16-float (64B) aligned rows ----------------
__global__ void edge_A16_kernel(const float* __restrict__ dist,
                                const int* __restrict__ eidx,   // [2,E]
                                const float* __restrict__ gate, // [N,9]
                                float* __restrict__ A,          // [E,16]
                                int E) {
    int e = blockIdx.x * blockDim.x + threadIdx.x;
    if (e >= E) return;
    float rik = dist[e];
    float fcik = fcut(rik);
    int nk = eidx[E + e];
    const float* g = gate + (size_t)nk * 9;
    float rr = rik * CUTOFF_INV;
    float v[9];

    {   // l = 0: j0 = sin(x)/x
        const float Z0[3] = {3.14159265358979324f, 6.28318530717958648f, 9.42477796076937972f};
#pragma unroll
        for (int n = 0; n < 3; ++n) {
            float x = Z0[n] * rr;
            v[n] = (__sinf(x) / x) * fcik * g[n];
        }
    }
    {   // l = 1: j1 = (sin/x - cos)/x
        const float Z1[3] = {4.49340945790806150f, 7.72525183693865170f, 10.9041216594298970f};
#pragma unroll
        for (int n = 0; n < 3; ++n) {
            float x = Z1[n] * rr;
            float s, c;
            __sincosf(x, &s, &c);
            float invx = 1.0f / x;
            v[3 + n] = ((s * invx - c) * invx) * fcik * g[3 + n];
        }
    }
    {   // l = 2: j2 = 3/x*j1 - j0
        const float Z2[3] = {5.76345919689554900f, 9.09501133047736000f, 12.3229409705673230f};
#pragma unroll
        for (int n = 0; n < 3; ++n) {
            float x = Z2[n] * rr;
            float s, c;
            __sincosf(x, &s, &c);
            float invx = 1.0f / x;
            float sx = s * invx;
            float j1 = (sx - c) * invx;
            v[6 + n] = (3.0f * invx * j1 - sx) * fcik * g[6 + n];
        }
    }
    float4* out = (float4*)(A + ((size_t)e << 4));
    out[0] = make_float4(v[0], v[1], v[2], v[3]);
    out[1] = make_float4(v[4], v[5], v[6], v[7]);
    out[2] = make_float4(v[8], 0.0f, 0.0f, 0.0f);
    out[3] = make_float4(0.0f, 0.0f, 0.0f, 0.0f);
}

// overflow fallback: accumulate one record straight into global mid
__device__ __forceinline__ void spill_rec(uint2 rec, int bin,
                                          const float* __restrict__ A,
                                          float* __restrict__ mid) {
    float ca = __uint_as_float(rec.x);
    uint ik  = rec.y & 0xFFFFFu;
    uint ijl = rec.y >> 20;
    float s0, s1, s2;
    legendre_s(ca, s0, s1, s2);
    const float* a = A + ((size_t)ik << 4);
    float* dst = mid + ((size_t)bin * EPB + ijl) * 9;
    atomicAdd(dst + 0, a[0] * s0);
    atomicAdd(dst + 1, a[1] * s0);
    atomicAdd(dst + 2, a[2] * s0);
    atomicAdd(dst + 3, a[3] * s1);
    atomicAdd(dst + 4, a[4] * s1);
    atomicAdd(dst + 5, a[5] * s1);
    atomicAdd(dst + 6, a[6] * s2);
    atomicAdd(dst + 7, a[7] * s2);
    atomicAdd(dst + 8, a[8] * s2);
}

// ---------------- Pass 1: block-local counting sort -> binned records ----------------
// Per block: chunk of 4096 triplets. LDS histogram -> one returning global atomic per
// (block,bin) on 64B-padded counters -> local prefix -> LDS sort by bin -> coalesced
// writeout of per-bin runs (~8 contiguous records each). No rounds, no retries.
__global__ void __launch_bounds__(P1_THREADS) p1_sort_kernel(
        const float* __restrict__ ang,
        const int* __restrict__ tidx, // [2,T]
        uint* __restrict__ gcount,    // [NBIN*GC_STRIDE]
        uint2* __restrict__ binbuf,   // [NBIN*BCAP]
        const float* __restrict__ A,
        float* __restrict__ mid,
        int T, int NBIN, int BCAP) {
    __shared__ uint hist[NBIN_MAX];
    __shared__ uint sc[NBIN_MAX];     // inclusive scan -> exclusive prefix
    __shared__ uint gbase[NBIN_MAX];
    __shared__ uint lcur[NBIN_MAX];
    __shared__ uint2 sbuf[P1_CHUNK];
    __shared__ ushort sbin[P1_CHUNK];

    int t0 = blockIdx.x * P1_CHUNK;
    int m = T - t0;
    if (m <= 0) return;
    if (m > P1_CHUNK) m = P1_CHUNK;
    int tid = threadIdx.x;

    for (int i = tid; i < NBIN; i += blockDim.x) { hist[i] = 0; lcur[i] = 0; }
    __syncthreads();

    // pass A: histogram (reads tidx row 0 only)
    for (int i = tid; i < m; i += blockDim.x)
        atomicAdd(&hist[((uint)tidx[t0 + i]) >> EPB_SHIFT], 1u);
    __syncthreads();

    // inclusive scan of hist into sc (NBIN <= blockDim)
    if (tid < NBIN) sc[tid] = hist[tid];
    __syncthreads();
    for (int off = 1; off < NBIN; off <<= 1) {
        uint v = 0;
        if (tid < NBIN) {
            v = sc[tid];
            if (tid >= off) v += sc[tid - off];
        }
        __syncthreads();
        if (tid < NBIN) sc[tid] = v;
        __syncthreads();
    }
    // exclusive prefix + global reservation
    uint ex = 0, h = 0;
    if (tid < NBIN) {
        h = hist[tid];
        ex = sc[tid] - h;
    }
    __syncthreads();
    if (tid < NBIN) {
        sc[tid] = ex;
        gbase[tid] = h ? atomicAdd(&gcount[tid * GC_STRIDE], h) : 0u;
    }
    __syncthreads();

    // pass B: place records into LDS, sorted by bin
    for (int i = tid; i < m; i += blockDim.x) {
        int t = t0 + i;
        uint ij = (uint)tidx[t];
        uint ik = (uint)tidx[T + t];
        float ca = ang[t];
        uint bin = ij >> EPB_SHIFT;
        uint loc = atomicAdd(&lcur[bin], 1u);
        uint p = sc[bin] + loc;
        sbuf[p] = make_uint2(__float_as_uint(ca), ((ij & (EPB - 1u)) << 20) | ik);
        sbin[p] = (ushort)bin;
    }
    __syncthreads();

    // pass C: coalesced writeout of sorted runs
    for (int i = tid; i < m; i += blockDim.x) {
        uint bin = sbin[i];
        uint2 rec = sbuf[i];
        uint slot = gbase[bin] + ((uint)i - sc[bin]);
        if (slot < (uint)BCAP)
            binbuf[(size_t)bin * BCAP + slot] = rec;
        else
            spill_rec(rec, bin, A, mid);
    }
}

// ---------------- Pass 2 (fused): per-bin accumulate in LDS, merge, GatedMLP epilogue ----------------
__global__ void __launch_bounds__(1024) p2_fused_kernel(const float* __restrict__ dist,
                                                        const float* __restrict__ A,      // [E,16]
                                                        const uint* __restrict__ gcount,  // [NBIN*GC_STRIDE]
                                                        const uint2* __restrict__ binbuf,
                                                        const float* __restrict__ mid,    // [E,9] spill acc
                                                        const float* __restrict__ attr,
                                                        const float* __restrict__ Wm,
                                                        const float* __restrict__ bm,
                                                        const float* __restrict__ Wg,
                                                        const float* __restrict__ bg,
                                                        float* __restrict__ out,
                                                        int E, int BCAP) {
    __shared__ float lmid[EPB * 9];   // 72 KB
    __shared__ float sWm[576], sWg[576], sbm[64], sbg[64];
    for (int i = threadIdx.x; i < 576; i += blockDim.x) {
        sWm[i] = Wm[i];
        sWg[i] = Wg[i];
    }
    if (threadIdx.x < 64) {
        sbm[threadIdx.x] = bm[threadIdx.x];
        sbg[threadIdx.x] = bg[threadIdx.x];
    }
    int b = blockIdx.x;
    int ebase = b << EPB_SHIFT;
    int ecnt = min(EPB, E - ebase);
    for (int i = threadIdx.x; i < EPB * 9; i += blockDim.x) lmid[i] = 0.0f;
    __syncthreads();

    uint n = gcount[b * GC_STRIDE];
    if (n > (uint)BCAP) n = (uint)BCAP;
    const uint2* rb = binbuf + (size_t)b * BCAP;
    uint bd = blockDim.x;
    uint i = threadIdx.x;

    for (; i + 3 * bd < n; i += 4 * bd) {
        uint2 r0 = rb[i];
        uint2 r1 = rb[i + bd];
        uint2 r2 = rb[i + 2 * bd];
        uint2 r3 = rb[i + 3 * bd];
        const float4* A0 = (const float4*)(A + ((size_t)(r0.y & 0xFFFFFu) << 4));
        const float4* A1 = (const float4*)(A + ((size_t)(r1.y & 0xFFFFFu) << 4));
        const float4* A2 = (const float4*)(A + ((size_t)(r2.y & 0xFFFFFu) << 4));
        const float4* A3 = (const float4*)(A + ((size_t)(r3.y & 0xFFFFFu) << 4));
        float4 a00 = A0[0], a01 = A0[1]; float a08 = *((const float*)(A0 + 2));
        float4 a10 = A1[0], a11 = A1[1]; float a18 = *((const float*)(A1 + 2));
        float4 a20 = A2[0], a21 = A2[1]; float a28 = *((const float*)(A2 + 2));
        float4 a30 = A3[0], a31 = A3[1]; float a38 = *((const float*)(A3 + 2));

#define ACC_ONE(rr, q0, q1, q8)                                       \
        {                                                             \
            float ca = __uint_as_float(rr.x);                         \
            uint ijl = rr.y >> 20;                                    \
            float s0, s1, s2;                                         \
            legendre_s(ca, s0, s1, s2);                               \
            float* d = &lmid[ijl * 9];                                \
            atomicAdd(d + 0, q0.x * s0);                              \
            atomicAdd(d + 1, q0.y * s0);                              \
            atomicAdd(d + 2, q0.z * s0);                              \
            atomicAdd(d + 3, q0.w * s1);                              \
            atomicAdd(d + 4, q1.x * s1);                              \
            atomicAdd(d + 5, q1.y * s1);                              \
            atomicAdd(d + 6, q1.z * s2);                              \
            atomicAdd(d + 7, q1.w * s2);                              \
            atomicAdd(d + 8, q8 * s2);                                \
        }

        ACC_ONE(r0, a00, a01, a08)
        ACC_ONE(r1, a10, a11, a18)
        ACC_ONE(r2, a20, a21, a28)
        ACC_ONE(r3, a30, a31, a38)
    }
    for (; i < n; i += bd) {
        uint2 rr = rb[i];
        const float4* Ar = (const float4*)(A + ((size_t)(rr.y & 0xFFFFFu) << 4));
        float4 q0 = Ar[0], q1 = Ar[1];
        float q8 = *((const float*)(Ar + 2));
        ACC_ONE(rr, q0, q1, q8)
    }
#undef ACC_ONE

    __syncthreads();
    // merge pass: fold fc(rij) and spill-mid into lmid with coalesced loads
    for (int el = threadIdx.x; el < ecnt; el += blockDim.x) {
        int e = ebase + el;
        float fc = fcut(dist[e]);
        const float* mg = mid + (size_t)e * 9;
        float* ls = &lmid[el * 9];
#pragma unroll
        for (int d = 0; d < 9; ++d) ls[d] = fc * (ls[d] + mg[d]);
    }
    __syncthreads();

    // GatedMLP epilogue: wave per edge, lane = feature; reads LDS only + streams attr/out.
    int wid  = threadIdx.x >> 6;
    int lane = threadIdx.x & 63;
    int nw   = blockDim.x >> 6;
    for (int el = wid; el < ecnt; el += nw) {
        int e = ebase + el;
        const float* ls = &lmid[el * 9];
        float am = sbm[lane], ag = sbg[lane];
#pragma unroll
        for (int d = 0; d < 9; ++d) {
            float ud = ls[d];
            am += ud * sWm[d * 64 + lane];
            ag += ud * sWg[d * 64 + lane];
        }
        float h  = am / (1.0f + __expf(-am));   // silu
        float gt = 1.0f / (1.0f + __expf(-ag)); // sigmoid
        size_t off = (size_t)e * 64 + lane;
        out[off] = attr[off] + h * gt;
    }
}

// ---------------- Legacy fallback triplet kernel (round-1 path) ----------------
__global__ void triplet_kernel(const float* __restrict__ dist,
                               const float* __restrict__ ang,
                               const int* __restrict__ tidx,
                               const int* __restrict__ eidx,
                               const float* __restrict__ gate,
                               float* __restrict__ mid,
                               int T, int E) {
    int t = blockIdx.x * blockDim.x + threadIdx.x;
    if (t >= T) return;
    int ij = tidx[t];
    int ik = tidx[T + t];
    float ca  = ang[t];
    float rij = dist[ij];
    float rik = dist[ik];
    float fc = fcut(rij) * fcut(rik);
    float s0, s1, s2;
    legendre_s(ca, s0, s1, s2);
    s0 *= fc; s1 *= fc; s2 *= fc;
    int nk = eidx[E + ik];
    const float* g = gate + (size_t)nk * 9;
    float rr = rik * CUTOFF_INV;
    float v[9];
    {
        const float Z0[3] = {3.14159265358979324f, 6.28318530717958648f, 9.42477796076937972f};
#pragma unroll
        for (int n = 0; n < 3; ++n) {
            float x = Z0[n] * rr;
            v[n] = (__sinf(x) / x) * s0 * g[n];
        }
    }
    {
        const float Z1[3] = {4.49340945790806150f, 7.72525183693865170f, 10.9041216594298970f};
#pragma unroll
        for (int n = 0; n < 3; ++n) {
            float x = Z1[n] * rr;
            float s, c;
            __sincosf(x, &s, &c);
            float invx = 1.0f / x;
            v[3 + n] = ((s * invx - c) * invx) * s1 * g[3 + n];
        }
    }
    {
        const float Z2[3] = {5.76345919689554900f, 9.09501133047736000f, 12.3229409705673230f};
#pragma unroll
        for (int n = 0; n < 3; ++n) {
            float x = Z2[n] * rr;
            float s, c;
            __sincosf(x, &s, &c);
            float invx = 1.0f / x;
            float sx = s * invx;
            float j1 = (sx - c) * invx;
            v[6 + n] = (3.0f * invx * j1 - sx) * s2 * g[6 + n];
        }
    }
    float* dst = mid + (size_t)ij * 9;
#pragma unroll
    for (int d = 0; d < 9; ++d) atomicAdd(dst + d, v[d]);
}

// ---------------- Legacy Stage 3 (fallback path only) ----------------
__global__ void edge_kernel(const float* __restrict__ mid,
                            const float* __restrict__ attr,
                            const float* __restrict__ Wm, const float* __restrict__ bm,
                            const float* __restrict__ Wg, const float* __restrict__ bg,
                            float* __restrict__ out, int E) {
    __shared__ float sWm[9 * 64], sWg[9 * 64], sbm[64], sbg[64];
    for (int i = threadIdx.x; i < 576; i += blockDim.x) {
        sWm[i] = Wm[i];
        sWg[i] = Wg[i];
    }
    if (threadIdx.x < 64) {
        sbm[threadIdx.x] = bm[threadIdx.x];
        sbg[threadIdx.x] = bg[threadIdx.x];
    }
    __syncthreads();
    int wid  = threadIdx.x >> 6;
    int lane = threadIdx.x & 63;
    int e = blockIdx.x * (blockDim.x >> 6) + wid;
    if (e >= E) return;
    const float* u = mid + (size_t)e * 9;
    float am = sbm[lane], ag = sbg[lane];
#pragma unroll
    for (int d = 0; d < 9; ++d) {
        float ud = u[d];
        am += ud * sWm[d * 64 + lane];
        ag += ud * sWg[d * 64 + lane];
    }
    float h  = am / (1.0f + __expf(-am));
    float gt = 1.0f / (1.0f + __expf(-ag));
    size_t off = (size_t)e * 64 + lane;
    out[off] = attr[off] + h * gt;
}

extern "C" void kernel_launch(void* const* d_in, const int* in_sizes, int n_in,
                              void* d_out, int out_size, void* d_ws, size_t ws_size,
                              hipStream_t stream) {
    const float* dist = (const float*)d_in[0];
    const float* ang  = (const float*)d_in[1];
    const float* nf   = (const float*)d_in[2];
    const float* attr = (const float*)d_in[3];
    const float* W1   = (const float*)d_in[4];
    const float* b1   = (const float*)d_in[5];
    const float* Wm   = (const float*)d_in[6];
    const float* bm   = (const float*)d_in[7];
    const float* Wg   = (const float*)d_in[8];
    const float* bg   = (const float*)d_in[9];
    const int* tidx   = (const int*)d_in[10];
    const int* eidx   = (const int*)d_in[11];

    int E = in_sizes[0];
    int T = in_sizes[1];
    int N = in_sizes[2] / 64;

    int NBIN = (E + EPB - 1) >> EPB_SHIFT;
    int mean = T / (NBIN > 0 ? NBIN : 1);
    int BCAP = ((mean + mean / 8 + 512) + 15) & ~15;   // ~20 sigma headroom, 16-aligned

    // ws layout (floats): gate[N*9 pad16] | A[E*16] | mid[E*9] | gcount[NBIN*16] | binbuf[NBIN*BCAP*2]
    size_t f_gate  = ((size_t)N * 9 + 15) & ~(size_t)15;
    size_t o_A     = f_gate;
    size_t o_mid   = o_A + (size_t)E * 16;
    size_t o_gcnt  = o_mid + (size_t)E * 9;
    size_t o_bb    = (o_gcnt + (size_t)NBIN * GC_STRIDE + 15) & ~(size_t)15;  // 64B-align binbuf
    size_t total   = o_bb + (size_t)NBIN * BCAP * 2;

    bool newpath = (E <= (1 << 20)) && (NBIN <= NBIN_MAX) && (NBIN <= P1_THREADS)
                   && (ws_size >= total * 4);

    float* gate = (float*)d_ws;

    if (newpath) {
        float* A      = gate + o_A;
        float* mid    = gate + o_mid;
        uint*  gcount = (uint*)(gate + o_gcnt);
        uint2* binbuf = (uint2*)(gate + o_bb);

        hipMemsetAsync(gcount, 0, (size_t)NBIN * GC_STRIDE * sizeof(uint), stream);
        hipMemsetAsync(mid, 0, (size_t)E * 9 * sizeof(float), stream);
        node_gate_kernel<<<(N + 255) / 256, 256, 0, stream>>>(nf, W1, b1, gate, N);
        edge_A16_kernel<<<(E + 255) / 256, 256, 0, stream>>>(dist, eidx, gate, A, E);

        int p1grid = (T + P1_CHUNK - 1) / P1_CHUNK;
        p1_sort_kernel<<<p1grid, P1_THREADS, 0, stream>>>(ang, tidx, gcount, binbuf, A, mid, T, NBIN, BCAP);
        p2_fused_kernel<<<NBIN, 1024, 0, stream>>>(dist, A, gcount, binbuf, mid,
                                                   attr, Wm, bm, Wg, bg,
                                                   (float*)d_out, E, BCAP);
    } else {
        // legacy path (round-1)
        float* mid = gate + f_gate;
        hipMemsetAsync(mid, 0, (size_t)E * 9 * sizeof(float), stream);
        node_gate_kernel<<<(N + 255) / 256, 256, 0, stream>>>(nf, W1, b1, gate, N);
        triplet_kernel<<<(T + 255) / 256, 256, 0, stream>>>(dist, ang, tidx, eidx, gate, mid, T, E);
        edge_kernel<<<(E + 3) / 4, 256, 0, stream>>>(mid, attr, Wm, bm, Wg, bg, (float*)d_out, E);
    }
}